// Round 1
// baseline (2005.379 us; speedup 1.0000x reference)
//
#include <hip/hip_runtime.h>
#include <math.h>

// ---------- helpers: order-preserving float<->uint for atomicMax ----------
__device__ __forceinline__ unsigned int fenc(float x) {
    int i = __float_as_int(x);
    return (i >= 0) ? ((unsigned int)i | 0x80000000u) : ~((unsigned int)i);
}
__device__ __forceinline__ float fdec(unsigned int u) {
    int i = (u & 0x80000000u) ? (int)(u & 0x7FFFFFFFu) : (int)(~u);
    return __int_as_float(i);
}

// ---------- tiled f32 GEMM: out[r][c] = sum_k A[r][k]*W[k][c], K=C=128 ----------
__global__ __launch_bounds__(256) void gemm_nc(const float* __restrict__ A,
                                               const float* __restrict__ W,
                                               float* __restrict__ out, int n_rows)
{
    __shared__ float a_sh[64][68];   // 64 rows x 64 k (half), padded
    __shared__ float b_sh[64][64];   // 64 k (half) x 64 cols
    const int tid = threadIdx.x;
    const int row0 = blockIdx.x * 64;
    const int cb   = blockIdx.y * 64;
    const int tr = (tid >> 4) * 4;
    const int tc = (tid & 15) * 4;
    float acc[4][4] = {};
    for (int kh = 0; kh < 2; ++kh) {
        __syncthreads();
        for (int i = 0; i < 4; ++i) {
            int f = tid + i * 256;
            int r = f >> 4, c4 = (f & 15) * 4;
            float4 v = make_float4(0.f, 0.f, 0.f, 0.f);
            if (row0 + r < n_rows)
                v = *(const float4*)(A + (size_t)(row0 + r) * 128 + kh * 64 + c4);
            *(float4*)&a_sh[r][c4] = v;
        }
        for (int i = 0; i < 4; ++i) {
            int f = tid + i * 256;
            int k = f >> 4, c4 = (f & 15) * 4;
            *(float4*)&b_sh[k][c4] = *(const float4*)(W + (size_t)(kh * 64 + k) * 128 + cb + c4);
        }
        __syncthreads();
        #pragma unroll
        for (int k4 = 0; k4 < 16; ++k4) {
            float4 a[4], b[4];
            #pragma unroll
            for (int i = 0; i < 4; ++i) a[i] = *(float4*)&a_sh[tr + i][k4 * 4];
            #pragma unroll
            for (int kk = 0; kk < 4; ++kk) b[kk] = *(float4*)&b_sh[k4 * 4 + kk][tc];
            #pragma unroll
            for (int i = 0; i < 4; ++i) {
                const float av[4] = {a[i].x, a[i].y, a[i].z, a[i].w};
                #pragma unroll
                for (int kk = 0; kk < 4; ++kk) {
                    acc[i][0] = fmaf(av[kk], b[kk].x, acc[i][0]);
                    acc[i][1] = fmaf(av[kk], b[kk].y, acc[i][1]);
                    acc[i][2] = fmaf(av[kk], b[kk].z, acc[i][2]);
                    acc[i][3] = fmaf(av[kk], b[kk].w, acc[i][3]);
                }
            }
        }
    }
    for (int i = 0; i < 4; ++i) {
        int r = row0 + tr + i;
        if (r < n_rows) {
            float4 v = make_float4(acc[i][0], acc[i][1], acc[i][2], acc[i][3]);
            *(float4*)(out + (size_t)r * 128 + cb + tc) = v;
        }
    }
}

// ---------- pass 1: per-edge attention score + segment max ----------
// one wave (64 lanes) per edge; lane l owns elements l (heads 0/1) and 64+l (heads 2/3)
__global__ __launch_bounds__(256) void score_kernel(
    const float* __restrict__ Q, const float* __restrict__ K,
    const float* __restrict__ att, const int* __restrict__ head,
    const int* __restrict__ tail, const int* __restrict__ etyp,
    float* __restrict__ score, unsigned int* __restrict__ segmax, int E)
{
    int wid = (blockIdx.x * 256 + threadIdx.x) >> 6;
    if (wid >= E) return;
    int l = threadIdx.x & 63;
    int hn = head[wid], tn = tail[wid], rel = etyp[wid] - 1;
    const float* qrow = Q + (size_t)hn * 128;
    const float* krow = K + (size_t)tn * 128;
    float q0 = qrow[l], q1 = qrow[64 + l];
    float k0 = krow[l], k1 = krow[64 + l];
    const float* Ab = att + (size_t)rel * 4096;
    int kk = l & 31;
    int base = l & 32;
    float sc[2];
    #pragma unroll
    for (int s = 0; s < 2; ++s) {
        float kv = s ? k1 : k0;
        float qv = s ? q1 : q0;
        int h = s * 2 + (l >> 5);
        const float* Ah = Ab + h * 1024 + kk;
        float kp = 0.f;
        #pragma unroll
        for (int d = 0; d < 32; ++d) {
            float kd = __shfl(kv, base + d, 64);
            kp = fmaf(kd, Ah[d * 32], kp);
        }
        float p = qv * kp;
        #pragma unroll
        for (int off = 16; off >= 1; off >>= 1) p += __shfl_xor(p, off, 64);
        sc[s] = p * 0.17677669529663687f;  // 1/sqrt(32)
    }
    if (kk == 0) {
        #pragma unroll
        for (int s = 0; s < 2; ++s) {
            int h = s * 2 + (l >> 5);
            score[(size_t)wid * 4 + h] = sc[s];
            atomicMax(segmax + (size_t)hn * 4 + h, fenc(sc[s]));
        }
    }
}

// ---------- pass 2: exp + denom ----------
__global__ __launch_bounds__(256) void exdenom_kernel(
    float* __restrict__ sc, const unsigned int* __restrict__ seg,
    float* __restrict__ den, const int* __restrict__ head, int E)
{
    int t = blockIdx.x * 256 + threadIdx.x;
    if (t >= E * 4) return;
    int e = t >> 2, h = t & 3;
    int hn = head[e];
    float m = fdec(seg[(size_t)hn * 4 + h]);
    float v = expf(sc[t] - m);
    sc[t] = v;
    atomicAdd(den + (size_t)hn * 4 + h, v);
}

// ---------- pass 3: message transform + weighted scatter ----------
__global__ __launch_bounds__(256) void msg_kernel(
    const float* __restrict__ V, const float* __restrict__ msg,
    const int* __restrict__ head, const int* __restrict__ tail,
    const int* __restrict__ etyp, const float* __restrict__ ex,
    const float* __restrict__ den, float* __restrict__ M, int E)
{
    int wid = (blockIdx.x * 256 + threadIdx.x) >> 6;
    if (wid >= E) return;
    int l = threadIdx.x & 63;
    int hn = head[wid], tn = tail[wid], rel = etyp[wid] - 1;
    const float* vrow = V + (size_t)tn * 128;
    float v0 = vrow[l], v1 = vrow[64 + l];
    const float* Mb = msg + (size_t)rel * 4096;
    int kk = l & 31;
    int base = l & 32;
    #pragma unroll
    for (int s = 0; s < 2; ++s) {
        float vv = s ? v1 : v0;
        int h = s * 2 + (l >> 5);
        const float* Mh = Mb + h * 1024 + kk;
        float vp = 0.f;
        #pragma unroll
        for (int d = 0; d < 32; ++d) {
            float vd = __shfl(vv, base + d, 64);
            vp = fmaf(vd, Mh[d * 32], vp);
        }
        float a = ex[(size_t)wid * 4 + h] / den[(size_t)hn * 4 + h];
        atomicAdd(M + (size_t)hn * 128 + s * 64 + l, vp * a);
    }
}

// ---------- pass 5: user aggregation (sparse SpMM) ----------
__global__ __launch_bounds__(256) void user_kernel(
    const float* __restrict__ emb, const int* __restrict__ rows,
    const int* __restrict__ cols, const float* __restrict__ vals,
    float* __restrict__ out, int NNZ)
{
    int wid = (blockIdx.x * 256 + threadIdx.x) >> 6;
    if (wid >= NNZ) return;
    int l = threadIdx.x & 63;
    int r = rows[wid], c = cols[wid];
    float v = vals[wid];
    float2 e = *(const float2*)(emb + (size_t)c * 128 + l * 2);
    atomicAdd(out + (size_t)r * 128 + l * 2 + 0, e.x * v);
    atomicAdd(out + (size_t)r * 128 + l * 2 + 1, e.y * v);
}

extern "C" void kernel_launch(void* const* d_in, const int* in_sizes, int n_in,
                              void* d_out, int out_size, void* d_ws, size_t ws_size,
                              hipStream_t stream)
{
    const float* emb = (const float*)d_in[0];
    const float* W_Q = (const float*)d_in[1];
    const float* W_K = (const float*)d_in[2];
    const float* W_V = (const float*)d_in[3];
    const float* W_O = (const float*)d_in[4];
    const float* att = (const float*)d_in[5];
    const float* msg = (const float*)d_in[6];
    const int* eidx  = (const int*)d_in[8];
    const int* etyp  = (const int*)d_in[9];
    const int* irow  = (const int*)d_in[10];
    const int* icol  = (const int*)d_in[11];
    const float* ival = (const float*)d_in[12];

    const int N   = in_sizes[0] / 128;
    const int E   = in_sizes[8] / 2;
    const int NNZ = in_sizes[10];
    const int NU  = out_size / 128 - N;

    const int* head = eidx;
    const int* tail = eidx + E;

    // workspace layout (floats): Q (reused as M), K, V, SC, SEG, DEN
    float* Q  = (float*)d_ws;
    float* K  = Q + (size_t)N * 128;
    float* V  = K + (size_t)N * 128;
    float* SC = V + (size_t)N * 128;                       // E*4
    unsigned int* SEG = (unsigned int*)(SC + (size_t)E * 4); // N*4
    float* DEN = (float*)(SEG + (size_t)N * 4);            // N*4
    float* M = Q;  // alias: Q dead after score_kernel

    float* out_ent = (float*)d_out;
    float* out_usr = out_ent + (size_t)N * 128;

    // zero: segmax(+denom) and user output
    hipMemsetAsync(SEG, 0, (size_t)N * 4 * sizeof(unsigned int) * 2, stream);
    hipMemsetAsync(out_usr, 0, (size_t)NU * 128 * sizeof(float), stream);

    dim3 g_gemm((unsigned)((N + 63) / 64), 2);
    gemm_nc<<<g_gemm, 256, 0, stream>>>(emb, W_Q, Q, N);
    gemm_nc<<<g_gemm, 256, 0, stream>>>(emb, W_K, K, N);
    gemm_nc<<<g_gemm, 256, 0, stream>>>(emb, W_V, V, N);

    int ew_blocks = (E + 3) / 4;
    score_kernel<<<ew_blocks, 256, 0, stream>>>(Q, K, att, head, tail, etyp, SC, SEG, E);

    // Q is dead now; zero it for use as M accumulator
    hipMemsetAsync(M, 0, (size_t)N * 128 * sizeof(float), stream);

    exdenom_kernel<<<(E * 4 + 255) / 256, 256, 0, stream>>>(SC, SEG, DEN, head, E);
    msg_kernel<<<ew_blocks, 256, 0, stream>>>(V, msg, head, tail, etyp, SC, DEN, M, E);
    gemm_nc<<<g_gemm, 256, 0, stream>>>(M, W_O, out_ent, N);
    user_kernel<<<(NNZ + 3) / 4, 256, 0, stream>>>(emb, irow, icol, ival, out_usr, NNZ);
}

// Round 2
// 1542.106 us; speedup vs baseline: 1.3004x; 1.3004x over previous
//
#include <hip/hip_runtime.h>
#include <math.h>

// ---------- tiled f32 GEMM: out[r][c] = sum_k A[r][k]*W[k][c], K=C=128 ----------
__global__ __launch_bounds__(256) void gemm_nc(const float* __restrict__ A,
                                               const float* __restrict__ W,
                                               float* __restrict__ out, int n_rows)
{
    __shared__ float a_sh[64][68];
    __shared__ float b_sh[64][64];
    const int tid = threadIdx.x;
    const int row0 = blockIdx.x * 64;
    const int cb   = blockIdx.y * 64;
    const int tr = (tid >> 4) * 4;
    const int tc = (tid & 15) * 4;
    float acc[4][4] = {};
    for (int kh = 0; kh < 2; ++kh) {
        __syncthreads();
        for (int i = 0; i < 4; ++i) {
            int f = tid + i * 256;
            int r = f >> 4, c4 = (f & 15) * 4;
            float4 v = make_float4(0.f, 0.f, 0.f, 0.f);
            if (row0 + r < n_rows)
                v = *(const float4*)(A + (size_t)(row0 + r) * 128 + kh * 64 + c4);
            *(float4*)&a_sh[r][c4] = v;
        }
        for (int i = 0; i < 4; ++i) {
            int f = tid + i * 256;
            int k = f >> 4, c4 = (f & 15) * 4;
            *(float4*)&b_sh[k][c4] = *(const float4*)(W + (size_t)(kh * 64 + k) * 128 + cb + c4);
        }
        __syncthreads();
        #pragma unroll
        for (int k4 = 0; k4 < 16; ++k4) {
            float4 a[4], b[4];
            #pragma unroll
            for (int i = 0; i < 4; ++i) a[i] = *(float4*)&a_sh[tr + i][k4 * 4];
            #pragma unroll
            for (int kk = 0; kk < 4; ++kk) b[kk] = *(float4*)&b_sh[k4 * 4 + kk][tc];
            #pragma unroll
            for (int i = 0; i < 4; ++i) {
                const float av[4] = {a[i].x, a[i].y, a[i].z, a[i].w};
                #pragma unroll
                for (int kk = 0; kk < 4; ++kk) {
                    acc[i][0] = fmaf(av[kk], b[kk].x, acc[i][0]);
                    acc[i][1] = fmaf(av[kk], b[kk].y, acc[i][1]);
                    acc[i][2] = fmaf(av[kk], b[kk].z, acc[i][2]);
                    acc[i][3] = fmaf(av[kk], b[kk].w, acc[i][3]);
                }
            }
        }
    }
    for (int i = 0; i < 4; ++i) {
        int r = row0 + tr + i;
        if (r < n_rows) {
            float4 v = make_float4(acc[i][0], acc[i][1], acc[i][2], acc[i][3]);
            *(float4*)(out + (size_t)r * 128 + cb + tc) = v;
        }
    }
}

// ---------- per-edge attention score (no atomics) ----------
__global__ __launch_bounds__(256) void score_kernel(
    const float* __restrict__ Q, const float* __restrict__ K,
    const float* __restrict__ att, const int* __restrict__ head,
    const int* __restrict__ tail, const int* __restrict__ etyp,
    float* __restrict__ score, int E)
{
    int wid = (blockIdx.x * 256 + threadIdx.x) >> 6;
    if (wid >= E) return;
    int l = threadIdx.x & 63;
    int hn = head[wid], tn = tail[wid], rel = etyp[wid] - 1;
    const float* qrow = Q + (size_t)hn * 128;
    const float* krow = K + (size_t)tn * 128;
    float q0 = qrow[l], q1 = qrow[64 + l];
    float k0 = krow[l], k1 = krow[64 + l];
    const float* Ab = att + (size_t)rel * 4096;
    int kk = l & 31;
    int base = l & 32;
    #pragma unroll
    for (int s = 0; s < 2; ++s) {
        float kv = s ? k1 : k0;
        float qv = s ? q1 : q0;
        int h = s * 2 + (l >> 5);
        const float* Ah = Ab + h * 1024 + kk;
        float kp = 0.f;
        #pragma unroll
        for (int d = 0; d < 32; ++d) {
            float kd = __shfl(kv, base + d, 64);
            kp = fmaf(kd, Ah[d * 32], kp);
        }
        float p = qv * kp;
        #pragma unroll
        for (int off = 16; off >= 1; off >>= 1) p += __shfl_xor(p, off, 64);
        if (kk == 0) score[(size_t)wid * 4 + h] = p * 0.17677669529663687f;
    }
}

// ---------- CSR build: count / scan (3-phase) / fill ----------
__global__ __launch_bounds__(256) void bin_count(const int* __restrict__ keys,
                                                 unsigned* __restrict__ cnt, int n)
{
    int i = blockIdx.x * 256 + threadIdx.x;
    if (i < n) atomicAdd(&cnt[keys[i]], 1u);
}

__global__ __launch_bounds__(1024) void scan1(const unsigned* __restrict__ in,
                                              unsigned* __restrict__ out,
                                              unsigned* __restrict__ bsum, int n)
{
    __shared__ unsigned sh[1024];
    int i = blockIdx.x * 1024 + threadIdx.x;
    unsigned v = (i < n) ? in[i] : 0u;
    sh[threadIdx.x] = v;
    __syncthreads();
    for (int off = 1; off < 1024; off <<= 1) {
        unsigned t = (threadIdx.x >= (unsigned)off) ? sh[threadIdx.x - off] : 0u;
        __syncthreads();
        sh[threadIdx.x] += t;
        __syncthreads();
    }
    if (i < n) out[i] = sh[threadIdx.x] - v;  // exclusive
    if (threadIdx.x == 1023) bsum[blockIdx.x] = sh[1023];
}

__global__ __launch_bounds__(1024) void scan2(unsigned* __restrict__ bsum, int nb)
{
    __shared__ unsigned sh[1024];
    unsigned v = (threadIdx.x < (unsigned)nb) ? bsum[threadIdx.x] : 0u;
    sh[threadIdx.x] = v;
    __syncthreads();
    for (int off = 1; off < 1024; off <<= 1) {
        unsigned t = (threadIdx.x >= (unsigned)off) ? sh[threadIdx.x - off] : 0u;
        __syncthreads();
        sh[threadIdx.x] += t;
        __syncthreads();
    }
    if (threadIdx.x < (unsigned)nb) bsum[threadIdx.x] = sh[threadIdx.x] - v;  // exclusive
}

__global__ __launch_bounds__(1024) void scan3(unsigned* __restrict__ out,
                                              const unsigned* __restrict__ bsum, int n)
{
    int i = blockIdx.x * 1024 + threadIdx.x;
    if (i < n) out[i] += bsum[blockIdx.x];
}

__global__ __launch_bounds__(256) void fill_user(const int* __restrict__ rows,
                                                 const int* __restrict__ cols,
                                                 const float* __restrict__ vals,
                                                 unsigned* __restrict__ cursor,
                                                 int* __restrict__ pcol,
                                                 float* __restrict__ pval, int n)
{
    int i = blockIdx.x * 256 + threadIdx.x;
    if (i >= n) return;
    unsigned p = atomicAdd(&cursor[rows[i]], 1u);
    pcol[p] = cols[i];
    pval[p] = vals[i];
}

__global__ __launch_bounds__(256) void fill_edge(const int* __restrict__ keys,
                                                 unsigned* __restrict__ cursor,
                                                 int* __restrict__ perm, int n)
{
    int i = blockIdx.x * 256 + threadIdx.x;
    if (i >= n) return;
    unsigned p = atomicAdd(&cursor[keys[i]], 1u);
    perm[p] = i;
}

// ---------- per-node: softmax + message transform + accumulate (no atomics) ----------
__global__ __launch_bounds__(256) void node_kernel(
    const float* __restrict__ V, const float* __restrict__ msg,
    const int* __restrict__ tail, const int* __restrict__ etyp,
    const float* __restrict__ sc, const unsigned* __restrict__ ecur,
    const int* __restrict__ perm, float* __restrict__ M, int n)
{
    int node = (blockIdx.x * 256 + threadIdx.x) >> 6;
    if (node >= n) return;
    int l = threadIdx.x & 63;
    unsigned beg = node ? ecur[node - 1] : 0u;
    unsigned end = ecur[node];
    int h0 = (l >> 5);        // head for s=0
    int h1 = 2 + (l >> 5);    // head for s=1
    float mx0 = -INFINITY, mx1 = -INFINITY;
    for (unsigned j = beg; j < end; ++j) {
        int e = perm[j];
        mx0 = fmaxf(mx0, sc[(size_t)e * 4 + h0]);
        mx1 = fmaxf(mx1, sc[(size_t)e * 4 + h1]);
    }
    float dn0 = 0.f, dn1 = 0.f;
    for (unsigned j = beg; j < end; ++j) {
        int e = perm[j];
        dn0 += expf(sc[(size_t)e * 4 + h0] - mx0);
        dn1 += expf(sc[(size_t)e * 4 + h1] - mx1);
    }
    float acc0 = 0.f, acc1 = 0.f;
    int kk = l & 31;
    int base = l & 32;
    for (unsigned j = beg; j < end; ++j) {
        int e = perm[j];
        int tn = tail[e], rel = etyp[e] - 1;
        const float* vrow = V + (size_t)tn * 128;
        float v0 = vrow[l], v1 = vrow[64 + l];
        const float* Mb = msg + (size_t)rel * 4096;
        {
            const float* Mh = Mb + h0 * 1024 + kk;
            float vp = 0.f;
            #pragma unroll
            for (int d = 0; d < 32; ++d) {
                float vd = __shfl(v0, base + d, 64);
                vp = fmaf(vd, Mh[d * 32], vp);
            }
            float a = expf(sc[(size_t)e * 4 + h0] - mx0) / dn0;
            acc0 = fmaf(vp, a, acc0);
        }
        {
            const float* Mh = Mb + h1 * 1024 + kk;
            float vp = 0.f;
            #pragma unroll
            for (int d = 0; d < 32; ++d) {
                float vd = __shfl(v1, base + d, 64);
                vp = fmaf(vd, Mh[d * 32], vp);
            }
            float a = expf(sc[(size_t)e * 4 + h1] - mx1) / dn1;
            acc1 = fmaf(vp, a, acc1);
        }
    }
    M[(size_t)node * 128 + l] = acc0;
    M[(size_t)node * 128 + 64 + l] = acc1;
}

// ---------- per-user gather ----------
__global__ __launch_bounds__(256) void user_gather(
    const float* __restrict__ emb, const unsigned* __restrict__ ucur,
    const int* __restrict__ pcol, const float* __restrict__ pval,
    float* __restrict__ out, int nu)
{
    int u = (blockIdx.x * 256 + threadIdx.x) >> 6;
    if (u >= nu) return;
    int l = threadIdx.x & 63;
    unsigned beg = u ? ucur[u - 1] : 0u;
    unsigned end = ucur[u];
    float a0 = 0.f, a1 = 0.f;
    for (unsigned j = beg; j < end; ++j) {
        int c = pcol[j];
        float v = pval[j];
        float2 e = *(const float2*)(emb + (size_t)c * 128 + l * 2);
        a0 = fmaf(e.x, v, a0);
        a1 = fmaf(e.y, v, a1);
    }
    *(float2*)(out + (size_t)u * 128 + l * 2) = make_float2(a0, a1);
}

extern "C" void kernel_launch(void* const* d_in, const int* in_sizes, int n_in,
                              void* d_out, int out_size, void* d_ws, size_t ws_size,
                              hipStream_t stream)
{
    const float* emb = (const float*)d_in[0];
    const float* W_Q = (const float*)d_in[1];
    const float* W_K = (const float*)d_in[2];
    const float* W_V = (const float*)d_in[3];
    const float* W_O = (const float*)d_in[4];
    const float* att = (const float*)d_in[5];
    const float* msg = (const float*)d_in[6];
    const int* eidx  = (const int*)d_in[8];
    const int* etyp  = (const int*)d_in[9];
    const int* irow  = (const int*)d_in[10];
    const int* icol  = (const int*)d_in[11];
    const float* ival = (const float*)d_in[12];

    const int N   = in_sizes[0] / 128;
    const int E   = in_sizes[8] / 2;
    const int NNZ = in_sizes[10];
    const int NU  = out_size / 128 - N;

    const int* head = eidx;
    const int* tail = eidx + E;

    // workspace: Q (reused as M), K (reused as CSR scratch), V, SC
    float* Q  = (float*)d_ws;
    float* K  = Q + (size_t)N * 128;
    float* V  = K + (size_t)N * 128;
    float* SC = V + (size_t)N * 128;   // E*4 floats
    float* M  = Q;                     // alias: Q dead after score_kernel

    // CSR scratch inside K's buffer (K dead after score_kernel); sizes rounded up
    unsigned* ucnt  = (unsigned*)K;                 // NU
    unsigned* ecnt  = ucnt + 50048;                 // N
    unsigned* bsumU = ecnt + 100096;                // <=1024
    unsigned* bsumE = bsumU + 1024;                 // <=1024
    int*      pcol  = (int*)(bsumE + 1024);         // NNZ
    float*    pval  = (float*)(pcol + NNZ);         // NNZ
    int*      perm  = (int*)(pval + NNZ);           // E

    float* out_ent = (float*)d_out;
    float* out_usr = out_ent + (size_t)N * 128;

    dim3 g_gemm((unsigned)((N + 63) / 64), 2);
    gemm_nc<<<g_gemm, 256, 0, stream>>>(emb, W_Q, Q, N);
    gemm_nc<<<g_gemm, 256, 0, stream>>>(emb, W_K, K, N);
    gemm_nc<<<g_gemm, 256, 0, stream>>>(emb, W_V, V, N);

    int ew_blocks = (E + 3) / 4;
    score_kernel<<<ew_blocks, 256, 0, stream>>>(Q, K, att, head, tail, etyp, SC, E);

    // ---- K and Q now dead; build CSRs in K-space ----
    hipMemsetAsync(ucnt, 0, (size_t)NU * sizeof(unsigned), stream);
    hipMemsetAsync(ecnt, 0, (size_t)N * sizeof(unsigned), stream);

    bin_count<<<(NNZ + 255) / 256, 256, 0, stream>>>(irow, ucnt, NNZ);
    bin_count<<<(E + 255) / 256, 256, 0, stream>>>(head, ecnt, E);

    int nbU = (NU + 1023) / 1024, nbE = (N + 1023) / 1024;
    scan1<<<nbU, 1024, 0, stream>>>(ucnt, ucnt, bsumU, NU);
    scan2<<<1, 1024, 0, stream>>>(bsumU, nbU);
    scan3<<<nbU, 1024, 0, stream>>>(ucnt, bsumU, NU);
    scan1<<<nbE, 1024, 0, stream>>>(ecnt, ecnt, bsumE, N);
    scan2<<<1, 1024, 0, stream>>>(bsumE, nbE);
    scan3<<<nbE, 1024, 0, stream>>>(ecnt, bsumE, N);

    fill_user<<<(NNZ + 255) / 256, 256, 0, stream>>>(irow, icol, ival, ucnt, pcol, pval, NNZ);
    fill_edge<<<(E + 255) / 256, 256, 0, stream>>>(head, ecnt, perm, E);
    // post-fill, cursor[k] == end-boundary of bucket k (== start of bucket k+1)

    node_kernel<<<(N + 3) / 4, 256, 0, stream>>>(V, msg, tail, etyp, SC, ecnt, perm, M, N);
    gemm_nc<<<g_gemm, 256, 0, stream>>>(M, W_O, out_ent, N);
    user_gather<<<(NU + 3) / 4, 256, 0, stream>>>(emb, ucnt, pcol, pval, out_usr, NU);
}